// Round 5
// baseline (215.512 us; speedup 1.0000x reference)
//
#include <hip/hip_runtime.h>

#define HDIM  64
#define CELLS 16
#define ASTR  65                    // padded acc stride (floats) to spread banks
#define WPB   4                     // waves per block (256 threads)
#define PV    (CELLS * HDIM + CELLS)  // 1040
#define LCAP  96                    // per-wave list capacity (max 15+64=79)

// ws layout (floats): [0,1040) finalv | [1040,2064) m1k | [2064,2320) gconst0
//                     [2320,2576) sink | [2576, ...) partials (nbp * PV)
#define WS_M1K  1040
#define WS_G0   2064
#define WS_SINK 2320
#define WS_PART 2576

// ---------------------------------------------------------------------------
// Kernel 1: partial social pooling, batched-float4 edition.
// Per wave: contiguous agent range; per 64-agent window compute cell ids,
// append masked agents to a carry-over LDS list ((row<<4)|cell, absolute row),
// drain the list in 16-row batches: 4 x global_load_dwordx4 (1KB each, 16
// lanes/row) then ds_add_f32 accumulates into per-wave acc[16][65].
// No per-chunk serial tail; one <=15-row masked flush per wave at the end.
// ---------------------------------------------------------------------------
__global__ void __launch_bounds__(256, 4) k_pool(
    const float* __restrict__ all_h, const float2* __restrict__ pos2,
    const int* __restrict__ idxp, float* __restrict__ partial,
    int N, int nwaves)
{
    __shared__ float acc[WPB][CELLS * ASTR];  // 16.6 KB
    __shared__ float cnt[WPB][CELLS];
    __shared__ int   lst[WPB][LCAP];
    const int tid  = threadIdx.x;
    const int wave = tid >> 6;
    const int lane = tid & 63;

    for (int v = tid; v < WPB * CELLS * ASTR; v += 256) ((float*)acc)[v] = 0.0f;
    if (tid < WPB * CELLS) ((float*)cnt)[tid] = 0.0f;
    __syncthreads();

    const int    idx0 = idxp[0];
    const float2 p0   = pos2[idx0];
    const int    gw   = blockIdx.x * WPB + wave;
    // contiguous, balanced range [a0, a1)
    const int a0 = (int)((long long)gw * N / nwaves);
    const int a1 = (int)((long long)(gw + 1) * N / nwaves);
    float* __restrict__ accw = acc[wave];
    float* __restrict__ cntw = cnt[wave];
    int*   __restrict__ lstw = lst[wave];

    const int grp  = lane >> 4;   // which of 4 rows in a load batch
    const int colb = lane & 15;   // float4 index within the row
    int cnt_n = 0;                // list length (wave-uniform)

    // prefetch first window's positions
    float2 pn = (a0 + lane < a1) ? pos2[a0 + lane] : make_float2(1e30f, 1e30f);

    for (int base = a0; base < a1; base += 64) {
        const float2 p = pn;
        const int nb = base + 64;
        if (nb < a1)
            pn = (nb + lane < a1) ? pos2[nb + lane] : make_float2(1e30f, 1e30f);

        const int a = base + lane;
        int cellid = -1;
        if (a < a1 && a != idx0) {
            const float dx = p.x - p0.x;
            const float dy = p.y - p0.y;
            if (fmaxf(fabsf(dx), fabsf(dy)) <= 4.0f) {
                const float f0 = floorf((dx / 4.0f + 1.0f) / 2.0f * 4.0f);
                const float f1 = floorf((dy / 4.0f + 1.0f) / 2.0f * 4.0f);
                const int g0 = (int)fminf(fmaxf(f0, 0.0f), 3.0f);
                const int g1 = (int)fminf(fmaxf(f1, 0.0f), 3.0f);
                cellid = g1 * 4 + g0;
                atomicAdd(&cntw[cellid], 1.0f);  // exact int-in-f32
            }
        }
        const unsigned long long m = __ballot(cellid >= 0);
        if (cellid >= 0) {
            const int pos = cnt_n + __popcll(m & ((1ULL << lane) - 1ULL));
            lstw[pos] = (a << 4) | cellid;       // absolute row, 25 bits used
        }
        cnt_n += __popcll(m);

        // drain last-16 batches (LIFO keeps prefix intact; order is fixed)
        while (cnt_n >= 16) {
            cnt_n -= 16;
            float4 v0, v1, v2, v3;
            int c0, c1, c2, c3;
            {
                const int e = lstw[cnt_n + 0 * 4 + grp];
                c0 = e & 15;
                v0 = ((const float4*)(all_h + ((size_t)(e >> 4) << 6)))[colb];
            }
            {
                const int e = lstw[cnt_n + 1 * 4 + grp];
                c1 = e & 15;
                v1 = ((const float4*)(all_h + ((size_t)(e >> 4) << 6)))[colb];
            }
            {
                const int e = lstw[cnt_n + 2 * 4 + grp];
                c2 = e & 15;
                v2 = ((const float4*)(all_h + ((size_t)(e >> 4) << 6)))[colb];
            }
            {
                const int e = lstw[cnt_n + 3 * 4 + grp];
                c3 = e & 15;
                v3 = ((const float4*)(all_h + ((size_t)(e >> 4) << 6)))[colb];
            }
            float* a0p = accw + c0 * ASTR + colb * 4;
            atomicAdd(a0p + 0, v0.x); atomicAdd(a0p + 1, v0.y);
            atomicAdd(a0p + 2, v0.z); atomicAdd(a0p + 3, v0.w);
            float* a1p = accw + c1 * ASTR + colb * 4;
            atomicAdd(a1p + 0, v1.x); atomicAdd(a1p + 1, v1.y);
            atomicAdd(a1p + 2, v1.z); atomicAdd(a1p + 3, v1.w);
            float* a2p = accw + c2 * ASTR + colb * 4;
            atomicAdd(a2p + 0, v2.x); atomicAdd(a2p + 1, v2.y);
            atomicAdd(a2p + 2, v2.z); atomicAdd(a2p + 3, v2.w);
            float* a3p = accw + c3 * ASTR + colb * 4;
            atomicAdd(a3p + 0, v3.x); atomicAdd(a3p + 1, v3.y);
            atomicAdd(a3p + 2, v3.z); atomicAdd(a3p + 3, v3.w);
        }
    }

    // flush remainder (<16 rows), masked by row index
    {
        const int rem = cnt_n;
        #pragma unroll
        for (int j = 0; j < 4; ++j) {
            const int r = j * 4 + grp;
            if (r < rem) {
                const int e = lstw[r];
                const float4 vv =
                    ((const float4*)(all_h + ((size_t)(e >> 4) << 6)))[colb];
                float* ap = accw + (e & 15) * ASTR + colb * 4;
                atomicAdd(ap + 0, vv.x); atomicAdd(ap + 1, vv.y);
                atomicAdd(ap + 2, vv.z); atomicAdd(ap + 3, vv.w);
            }
        }
    }
    __syncthreads();

    float* __restrict__ outp = partial + (size_t)blockIdx.x * PV;
    for (int v = tid; v < CELLS * HDIM; v += 256) {
        const int c = v >> 6, col = v & 63;
        outp[v] = acc[0][c * ASTR + col] + acc[1][c * ASTR + col]
                + acc[2][c * ASTR + col] + acc[3][c * ASTR + col];
    }
    if (tid < CELLS)
        outp[CELLS * HDIM + tid] = cnt[0][tid] + cnt[1][tid] + cnt[2][tid] + cnt[3][tid];
}

// ---------------------------------------------------------------------------
// Kernel 2: blocks 0..64 fold nbp partials -> 1040 values, one float4-quad
// of values per wave (65 blocks x 4 waves = 260 quads = 1040 values).
// Block 65: prep m1k/gconst0 for the LSTM and warm its weights into L2.
// (R4 bug: grid was 260 reduce blocks with q=blockIdx*4+wave -> q*4 up to
//  4156 overwrote WS_M1K/WS_G0. Now 65 reduce blocks, q < 260 guaranteed.)
// ---------------------------------------------------------------------------
__global__ void __launch_bounds__(256) k_reduce(
    const float* __restrict__ partial, float* __restrict__ ws,
    const float* __restrict__ W_in, const float* __restrict__ b_in,
    const float* __restrict__ W_ih, const float* __restrict__ b_ih,
    const float* __restrict__ W_hh, const float* __restrict__ b_hh,
    const float* __restrict__ W_sp, const float* __restrict__ W_out,
    int nbp)
{
    const int tid = threadIdx.x;
    if (blockIdx.x < 65) {
        const int wave = tid >> 6;
        const int lane = tid & 63;
        const int q = blockIdx.x * 4 + wave;   // value-quad index, q < 260
        if (q * 4 >= PV) return;
        float s0 = 0.0f, s1 = 0.0f, s2 = 0.0f, s3 = 0.0f;
        for (int b = lane; b < nbp; b += 64) {
            const float4 t = *(const float4*)&partial[(size_t)b * PV + q * 4];
            s0 += t.x; s1 += t.y; s2 += t.z; s3 += t.w;
        }
        #pragma unroll
        for (int off = 32; off > 0; off >>= 1) {
            s0 += __shfl_xor(s0, off);
            s1 += __shfl_xor(s1, off);
            s2 += __shfl_xor(s2, off);
            s3 += __shfl_xor(s3, off);
        }
        if (lane == 0) {
            float4 r; r.x = s0; r.y = s1; r.z = s2; r.w = s3;
            *(float4*)&ws[q * 4] = r;
        }
        return;
    }
    // ---- prep block (blockIdx.x == 65) ----
    float m0 = 0.0f, m1 = 0.0f, m2 = 0.0f, m3 = 0.0f;
    float gc = b_ih[tid] + b_hh[tid];
    for (int m = 0; m < 64; m += 4) {
        const float4 w4 = *(const float4*)&W_ih[tid * 128 + m];
        const float4 q0 = *(const float4*)&W_in[m * 4];
        const float4 q1 = *(const float4*)&W_in[(m + 1) * 4];
        const float4 q2 = *(const float4*)&W_in[(m + 2) * 4];
        const float4 q3 = *(const float4*)&W_in[(m + 3) * 4];
        m0 += w4.x * q0.x + w4.y * q1.x + w4.z * q2.x + w4.w * q3.x;
        m1 += w4.x * q0.y + w4.y * q1.y + w4.z * q2.y + w4.w * q3.y;
        m2 += w4.x * q0.z + w4.y * q1.z + w4.z * q2.z + w4.w * q3.z;
        m3 += w4.x * q0.w + w4.y * q1.w + w4.z * q2.w + w4.w * q3.w;
        gc += w4.x * b_in[m] + w4.y * b_in[m + 1]
            + w4.z * b_in[m + 2] + w4.w * b_in[m + 3];
    }
    float4 mv; mv.x = m0; mv.y = m1; mv.z = m2; mv.w = m3;
    *(float4*)&ws[WS_M1K + tid * 4] = mv;
    ws[WS_G0 + tid] = gc;
    float warm = 0.0f;
    for (int k = 0; k < 64; k += 4) {
        const float4 a = *(const float4*)&W_ih[tid * 128 + 64 + k];
        const float4 b = *(const float4*)&W_hh[tid * 64 + k];
        warm += a.x + a.y + a.z + a.w + b.x + b.y + b.z + b.w;
    }
    for (int k = 0; k < 16; k += 4) {
        const float4 c = *(const float4*)&W_sp[tid * 16 + k];
        warm += c.x + c.y + c.z + c.w;
    }
    warm += W_out[tid & 127];
    ws[WS_SINK + tid] = warm;
}

// ---------------------------------------------------------------------------
// Kernel 3: pooled -> social -> 8 encoder + 12 decoder LSTM steps.
// (unchanged: precomputed m1k/gconst0, L2-warm weights,
//  2 barriers/encoder step, butterfly delta in decoder)
// ---------------------------------------------------------------------------
__global__ void __launch_bounds__(256) k_lstm(
    const float* __restrict__ ws, const float* __restrict__ history,
    const float* __restrict__ W_ih, const float* __restrict__ W_hh,
    const float* __restrict__ W_sp, const float* __restrict__ b_sp,
    const float* __restrict__ W_out, const float* __restrict__ b_out,
    float* __restrict__ out)
{
    __shared__ __align__(16) float pooled[64];
    __shared__ __align__(16) float social[64];
    __shared__ __align__(16) float hl[64];
    __shared__ __align__(16) float cl[64];
    __shared__ float gl[256];
    __shared__ __align__(16) float histl[32];
    __shared__ float xs[4];
    __shared__ float lp[2];
    const int tid = threadIdx.x;

    if (tid < 32) histl[tid] = history[tid];
    if (tid < 64) {
        float p = 0.0f;
        #pragma unroll
        for (int c = 0; c < CELLS; ++c) {
            const float cc = ws[CELLS * HDIM + c];
            p += ws[c * HDIM + tid] / fmaxf(cc, 1.0f);
        }
        pooled[tid] = p;
    }
    __syncthreads();
    if (tid < 64) {
        float s = b_sp[tid];
        for (int k = 0; k < 64; k += 4) {
            const float4 w4 = *(const float4*)&W_sp[tid * 64 + k];
            s += pooled[k] * w4.x + pooled[k + 1] * w4.y
               + pooled[k + 2] * w4.z + pooled[k + 3] * w4.w;
        }
        social[tid] = s;
        hl[tid] = 0.0f;
        cl[tid] = 0.0f;
    }
    if (tid == 0) { lp[0] = histl[28]; lp[1] = histl[29]; }
    __syncthreads();

    const float4 mv = *(const float4*)&ws[WS_M1K + tid * 4];
    float gconst = ws[WS_G0 + tid];
    for (int k = 0; k < 64; k += 4) {
        const float4 w4 = *(const float4*)&W_ih[tid * 128 + 64 + k];
        gconst += w4.x * social[k] + w4.y * social[k + 1]
                + w4.z * social[k + 2] + w4.w * social[k + 3];
    }
    float whh[64];
    #pragma unroll
    for (int k = 0; k < 64; k += 4) {
        const float4 w4 = *(const float4*)&W_hh[tid * 64 + k];
        whh[k] = w4.x; whh[k + 1] = w4.y; whh[k + 2] = w4.z; whh[k + 3] = w4.w;
    }
    float wout0 = 0.0f, wout1 = 0.0f, bo0 = 0.0f, bo1 = 0.0f;
    if (tid < 64) {
        wout0 = W_out[tid]; wout1 = W_out[64 + tid];
        bo0 = b_out[0]; bo1 = b_out[1];
    }
    __syncthreads();

    for (int t = 0; t < 8; ++t) {
        const float x0 = histl[t * 4 + 0], x1 = histl[t * 4 + 1];
        const float x2 = histl[t * 4 + 2], x3 = histl[t * 4 + 3];
        float g0 = gconst + mv.x * x0 + mv.y * x1;
        float g1 = mv.z * x2 + mv.w * x3;
        float g2 = 0.0f, g3 = 0.0f;
        #pragma unroll
        for (int k = 0; k < 64; k += 16) {
            const float4 a = *(const float4*)&hl[k];
            const float4 b = *(const float4*)&hl[k + 4];
            const float4 c = *(const float4*)&hl[k + 8];
            const float4 d = *(const float4*)&hl[k + 12];
            g0 += whh[k] * a.x + whh[k + 1] * a.y + whh[k + 2] * a.z + whh[k + 3] * a.w;
            g1 += whh[k + 4] * b.x + whh[k + 5] * b.y + whh[k + 6] * b.z + whh[k + 7] * b.w;
            g2 += whh[k + 8] * c.x + whh[k + 9] * c.y + whh[k + 10] * c.z + whh[k + 11] * c.w;
            g3 += whh[k + 12] * d.x + whh[k + 13] * d.y + whh[k + 14] * d.z + whh[k + 15] * d.w;
        }
        gl[tid] = (g0 + g1) + (g2 + g3);
        __syncthreads();
        if (tid < 64) {
            const float ig = 1.0f / (1.0f + expf(-gl[tid]));
            const float fg = 1.0f / (1.0f + expf(-gl[64 + tid]));
            const float gg = tanhf(gl[128 + tid]);
            const float og = 1.0f / (1.0f + expf(-gl[192 + tid]));
            const float cn = fg * cl[tid] + ig * gg;
            cl[tid] = cn;
            hl[tid] = og * tanhf(cn);
        }
        __syncthreads();
    }

    for (int t = 0; t < 12; ++t) {
        if (tid < 64) {
            float s0 = wout0 * hl[tid];
            float s1 = wout1 * hl[tid];
            #pragma unroll
            for (int off = 32; off > 0; off >>= 1) {
                s0 += __shfl_xor(s0, off);
                s1 += __shfl_xor(s1, off);
            }
            if (tid == 0) {
                const float d0 = s0 + bo0, d1 = s1 + bo1;
                out[t * 2 + 0] = d0;
                out[t * 2 + 1] = d1;
                const float n0 = lp[0] + d0, n1 = lp[1] + d1;
                xs[0] = n0; xs[1] = n1;
                xs[2] = d0 * 2.0f; xs[3] = d1 * 2.0f;
                lp[0] = n0; lp[1] = n1;
            }
        }
        __syncthreads();
        const float x0 = xs[0], x1 = xs[1], x2 = xs[2], x3 = xs[3];
        float g0 = gconst + mv.x * x0 + mv.y * x1;
        float g1 = mv.z * x2 + mv.w * x3;
        float g2 = 0.0f, g3 = 0.0f;
        #pragma unroll
        for (int k = 0; k < 64; k += 16) {
            const float4 a = *(const float4*)&hl[k];
            const float4 b = *(const float4*)&hl[k + 4];
            const float4 c = *(const float4*)&hl[k + 8];
            const float4 d = *(const float4*)&hl[k + 12];
            g0 += whh[k] * a.x + whh[k + 1] * a.y + whh[k + 2] * a.z + whh[k + 3] * a.w;
            g1 += whh[k + 4] * b.x + whh[k + 5] * b.y + whh[k + 6] * b.z + whh[k + 7] * b.w;
            g2 += whh[k + 8] * c.x + whh[k + 9] * c.y + whh[k + 10] * c.z + whh[k + 11] * c.w;
            g3 += whh[k + 12] * d.x + whh[k + 13] * d.y + whh[k + 14] * d.z + whh[k + 15] * d.w;
        }
        gl[tid] = (g0 + g1) + (g2 + g3);
        __syncthreads();
        if (tid < 64) {
            const float ig = 1.0f / (1.0f + expf(-gl[tid]));
            const float fg = 1.0f / (1.0f + expf(-gl[64 + tid]));
            const float gg = tanhf(gl[128 + tid]);
            const float og = 1.0f / (1.0f + expf(-gl[192 + tid]));
            const float cn = fg * cl[tid] + ig * gg;
            cl[tid] = cn;
            hl[tid] = og * tanhf(cn);
        }
        __syncthreads();
    }
}

extern "C" void kernel_launch(void* const* d_in, const int* in_sizes, int n_in,
                              void* d_out, int out_size, void* d_ws, size_t ws_size,
                              hipStream_t stream) {
    const float* history   = (const float*)d_in[0];
    const float* all_h     = (const float*)d_in[1];
    const float* positions = (const float*)d_in[2];
    const float* W_in  = (const float*)d_in[3];
    const float* b_in  = (const float*)d_in[4];
    const float* W_ih  = (const float*)d_in[5];
    const float* b_ih  = (const float*)d_in[6];
    const float* W_hh  = (const float*)d_in[7];
    const float* b_hh  = (const float*)d_in[8];
    const float* W_sp  = (const float*)d_in[9];
    const float* b_sp  = (const float*)d_in[10];
    const float* W_out = (const float*)d_in[11];
    const float* b_out = (const float*)d_in[12];
    const int*   idxp  = (const int*)d_in[13];
    const int N = in_sizes[2] / 2;

    float* ws      = (float*)d_ws;
    float* partial = ws + WS_PART;

    long long avail = (long long)(ws_size / sizeof(float)) - WS_PART;
    int nbp = 2048;
    if ((long long)nbp * PV > avail) nbp = (int)(avail / PV);
    if (nbp < 1) nbp = 1;

    k_pool<<<nbp, 256, 0, stream>>>(all_h, (const float2*)positions, idxp,
                                    partial, N, nbp * WPB);
    k_reduce<<<66, 256, 0, stream>>>(partial, ws, W_in, b_in, W_ih, b_ih,
                                     W_hh, b_hh, W_sp, W_out, nbp);
    k_lstm<<<1, 256, 0, stream>>>(ws, history, W_ih, W_hh, W_sp, b_sp,
                                  W_out, b_out, (float*)d_out);
}

// Round 6
// 72.393 us; speedup vs baseline: 2.9770x; 2.9770x over previous
//
#include <hip/hip_runtime.h>

#define HDIM  64
#define CELLS 16
#define WPB   4                       // waves per block (256 threads)
#define PV    (CELLS * HDIM + CELLS)  // 1040

// ws layout (floats): [0,1040) finalv | [1040,2064) m1k | [2064,2320) gconst0
//                     [2320,2576) sink | [2576, ...) partials (nbp * PV)
#define WS_M1K  1040
#define WS_G0   2064
#define WS_SINK 2320
#define WS_PART 2576

// ---------------------------------------------------------------------------
// Kernel 1: per-block partial social pooling (R3-proven structure).
// Last block (blockIdx == gridDim-1) instead runs the LSTM prep: fold
// m1k = W_ih[:,0:64]@W_in, gconst0 = b_ih+b_hh+W_ih[:,0:64]@b_in into ws and
// warm k_lstm's weights into L2 — hidden under the ~63us pool.
// Pool blocks: per 64-agent chunk compute cell ids, compact masked rows into
// a per-wave LDS list (ballot+prefix popcount), drain in 16-row batches of
// independent global_load_dword (16 x 256B in flight/wave), accumulate into
// per-wave acc[16][64] (lane = column, 2-way bank alias = free, no atomics).
// ---------------------------------------------------------------------------
__global__ void __launch_bounds__(256) k_pool(
    const float* __restrict__ all_h, const float2* __restrict__ pos2,
    const int* __restrict__ idxp, float* __restrict__ partial,
    float* __restrict__ ws,
    const float* __restrict__ W_in, const float* __restrict__ b_in,
    const float* __restrict__ W_ih, const float* __restrict__ b_ih,
    const float* __restrict__ W_hh, const float* __restrict__ b_hh,
    const float* __restrict__ W_sp, const float* __restrict__ W_out,
    int N, int nwaves)
{
    const int tid = threadIdx.x;

    if (blockIdx.x == gridDim.x - 1) {
        // ---- prep block: LSTM input-weight folds + L2 warm ----
        float m0 = 0.0f, m1 = 0.0f, m2 = 0.0f, m3 = 0.0f;
        float gc = b_ih[tid] + b_hh[tid];
        for (int m = 0; m < 64; m += 4) {
            const float4 w4 = *(const float4*)&W_ih[tid * 128 + m];
            const float4 q0 = *(const float4*)&W_in[m * 4];
            const float4 q1 = *(const float4*)&W_in[(m + 1) * 4];
            const float4 q2 = *(const float4*)&W_in[(m + 2) * 4];
            const float4 q3 = *(const float4*)&W_in[(m + 3) * 4];
            m0 += w4.x * q0.x + w4.y * q1.x + w4.z * q2.x + w4.w * q3.x;
            m1 += w4.x * q0.y + w4.y * q1.y + w4.z * q2.y + w4.w * q3.y;
            m2 += w4.x * q0.z + w4.y * q1.z + w4.z * q2.z + w4.w * q3.z;
            m3 += w4.x * q0.w + w4.y * q1.w + w4.z * q2.w + w4.w * q3.w;
            gc += w4.x * b_in[m] + w4.y * b_in[m + 1]
                + w4.z * b_in[m + 2] + w4.w * b_in[m + 3];
        }
        float4 mv; mv.x = m0; mv.y = m1; mv.z = m2; mv.w = m3;
        *(float4*)&ws[WS_M1K + tid * 4] = mv;
        ws[WS_G0 + tid] = gc;
        float warm = 0.0f;
        for (int k = 0; k < 64; k += 4) {
            const float4 a = *(const float4*)&W_ih[tid * 128 + 64 + k];
            const float4 b = *(const float4*)&W_hh[tid * 64 + k];
            warm += a.x + a.y + a.z + a.w + b.x + b.y + b.z + b.w;
        }
        for (int k = 0; k < 16; k += 4) {
            const float4 c = *(const float4*)&W_sp[tid * 16 + k];
            warm += c.x + c.y + c.z + c.w;
        }
        warm += W_out[tid & 127];
        ws[WS_SINK + tid] = warm;
        return;
    }

    __shared__ float acc[WPB][CELLS * HDIM];  // 16 KB
    __shared__ float cnt[WPB][CELLS];
    __shared__ __align__(16) int lst[WPB][64];
    const int wave = tid >> 6;
    const int lane = tid & 63;

    for (int v = tid; v < WPB * CELLS * HDIM; v += 256) ((float*)acc)[v] = 0.0f;
    if (tid < WPB * CELLS) ((float*)cnt)[tid] = 0.0f;
    __syncthreads();

    const int    idx0 = idxp[0];
    const float2 p0   = pos2[idx0];
    const int    gw   = blockIdx.x * WPB + wave;
    float* __restrict__ accw = acc[wave];
    int*   __restrict__ lstw = lst[wave];

    for (int base = gw * 64; base < N; base += nwaves * 64) {
        const int a = base + lane;
        int cellid = -1;
        if (a < N && a != idx0) {
            const float2 p = pos2[a];
            const float dx = p.x - p0.x;
            const float dy = p.y - p0.y;
            if (fmaxf(fabsf(dx), fabsf(dy)) <= 4.0f) {
                const float f0 = floorf((dx / 4.0f + 1.0f) / 2.0f * 4.0f);
                const float f1 = floorf((dy / 4.0f + 1.0f) / 2.0f * 4.0f);
                const int g0 = (int)fminf(fmaxf(f0, 0.0f), 3.0f);
                const int g1 = (int)fminf(fmaxf(f1, 0.0f), 3.0f);
                cellid = g1 * 4 + g0;
                atomicAdd(&cnt[wave][cellid], 1.0f);  // exact int-in-f32
            }
        }
        const unsigned long long m     = __ballot(cellid >= 0);
        const int                M     = __popcll(m);
        const unsigned long long below = m & ((1ULL << lane) - 1ULL);
        if (cellid >= 0) lstw[__popcll(below)] = (lane << 4) | cellid;
        // same-wave LDS write->read is in-order; no barrier needed

        const float* __restrict__ rowp = all_h + (size_t)base * HDIM + lane;
        int r = 0;
        for (; r + 16 <= M; r += 16) {
            const int4 e0 = *(const int4*)&lstw[r];
            const int4 e1 = *(const int4*)&lstw[r + 4];
            const int4 e2 = *(const int4*)&lstw[r + 8];
            const int4 e3 = *(const int4*)&lstw[r + 12];
            const float v0  = rowp[(size_t)(e0.x >> 4) * HDIM];
            const float v1  = rowp[(size_t)(e0.y >> 4) * HDIM];
            const float v2  = rowp[(size_t)(e0.z >> 4) * HDIM];
            const float v3  = rowp[(size_t)(e0.w >> 4) * HDIM];
            const float v4  = rowp[(size_t)(e1.x >> 4) * HDIM];
            const float v5  = rowp[(size_t)(e1.y >> 4) * HDIM];
            const float v6  = rowp[(size_t)(e1.z >> 4) * HDIM];
            const float v7  = rowp[(size_t)(e1.w >> 4) * HDIM];
            const float v8  = rowp[(size_t)(e2.x >> 4) * HDIM];
            const float v9  = rowp[(size_t)(e2.y >> 4) * HDIM];
            const float v10 = rowp[(size_t)(e2.z >> 4) * HDIM];
            const float v11 = rowp[(size_t)(e2.w >> 4) * HDIM];
            const float v12 = rowp[(size_t)(e3.x >> 4) * HDIM];
            const float v13 = rowp[(size_t)(e3.y >> 4) * HDIM];
            const float v14 = rowp[(size_t)(e3.z >> 4) * HDIM];
            const float v15 = rowp[(size_t)(e3.w >> 4) * HDIM];
            accw[(e0.x & 15) * HDIM + lane] += v0;
            accw[(e0.y & 15) * HDIM + lane] += v1;
            accw[(e0.z & 15) * HDIM + lane] += v2;
            accw[(e0.w & 15) * HDIM + lane] += v3;
            accw[(e1.x & 15) * HDIM + lane] += v4;
            accw[(e1.y & 15) * HDIM + lane] += v5;
            accw[(e1.z & 15) * HDIM + lane] += v6;
            accw[(e1.w & 15) * HDIM + lane] += v7;
            accw[(e2.x & 15) * HDIM + lane] += v8;
            accw[(e2.y & 15) * HDIM + lane] += v9;
            accw[(e2.z & 15) * HDIM + lane] += v10;
            accw[(e2.w & 15) * HDIM + lane] += v11;
            accw[(e3.x & 15) * HDIM + lane] += v12;
            accw[(e3.y & 15) * HDIM + lane] += v13;
            accw[(e3.z & 15) * HDIM + lane] += v14;
            accw[(e3.w & 15) * HDIM + lane] += v15;
        }
        for (; r + 8 <= M; r += 8) {
            const int4 e0 = *(const int4*)&lstw[r];
            const int4 e1 = *(const int4*)&lstw[r + 4];
            const float v0 = rowp[(size_t)(e0.x >> 4) * HDIM];
            const float v1 = rowp[(size_t)(e0.y >> 4) * HDIM];
            const float v2 = rowp[(size_t)(e0.z >> 4) * HDIM];
            const float v3 = rowp[(size_t)(e0.w >> 4) * HDIM];
            const float v4 = rowp[(size_t)(e1.x >> 4) * HDIM];
            const float v5 = rowp[(size_t)(e1.y >> 4) * HDIM];
            const float v6 = rowp[(size_t)(e1.z >> 4) * HDIM];
            const float v7 = rowp[(size_t)(e1.w >> 4) * HDIM];
            accw[(e0.x & 15) * HDIM + lane] += v0;
            accw[(e0.y & 15) * HDIM + lane] += v1;
            accw[(e0.z & 15) * HDIM + lane] += v2;
            accw[(e0.w & 15) * HDIM + lane] += v3;
            accw[(e1.x & 15) * HDIM + lane] += v4;
            accw[(e1.y & 15) * HDIM + lane] += v5;
            accw[(e1.z & 15) * HDIM + lane] += v6;
            accw[(e1.w & 15) * HDIM + lane] += v7;
        }
        for (; r < M; ++r) {
            const int e = lstw[r];
            accw[(e & 15) * HDIM + lane] += rowp[(size_t)(e >> 4) * HDIM];
        }
    }
    __syncthreads();

    float* __restrict__ outp = partial + (size_t)blockIdx.x * PV;
    for (int v = tid; v < CELLS * HDIM; v += 256)
        outp[v] = acc[0][v] + acc[1][v] + acc[2][v] + acc[3][v];
    if (tid < CELLS)
        outp[CELLS * HDIM + tid] = cnt[0][tid] + cnt[1][tid] + cnt[2][tid] + cnt[3][tid];
}

// ---------------------------------------------------------------------------
// Kernel 2: 65 blocks fold nbp partials -> 1040 values, one float4-quad of
// values per wave (65 x 4 waves = 260 quads = 1040 values). Fixed order ->
// deterministic. Partials are L2/L3-resident (8.5 MB).
// ---------------------------------------------------------------------------
__global__ void __launch_bounds__(256) k_reduce(
    const float* __restrict__ partial, float* __restrict__ ws, int nbp)
{
    const int tid  = threadIdx.x;
    const int wave = tid >> 6;
    const int lane = tid & 63;
    const int q = blockIdx.x * 4 + wave;   // quad index, q < 260
    if (q * 4 >= PV) return;
    float s0 = 0.0f, s1 = 0.0f, s2 = 0.0f, s3 = 0.0f;
    for (int b = lane; b < nbp; b += 64) {
        const float4 t = *(const float4*)&partial[(size_t)b * PV + q * 4];
        s0 += t.x; s1 += t.y; s2 += t.z; s3 += t.w;
    }
    #pragma unroll
    for (int off = 32; off > 0; off >>= 1) {
        s0 += __shfl_xor(s0, off);
        s1 += __shfl_xor(s1, off);
        s2 += __shfl_xor(s2, off);
        s3 += __shfl_xor(s3, off);
    }
    if (lane == 0) {
        float4 r; r.x = s0; r.y = s1; r.z = s2; r.w = s3;
        *(float4*)&ws[q * 4] = r;
    }
}

// ---------------------------------------------------------------------------
// Kernel 3: pooled -> social -> 8 encoder + 12 decoder LSTM steps.
// m1k/gconst0 precomputed by k_pool's prep block; weights L2-warm.
// ---------------------------------------------------------------------------
__global__ void __launch_bounds__(256) k_lstm(
    const float* __restrict__ ws, const float* __restrict__ history,
    const float* __restrict__ W_ih, const float* __restrict__ W_hh,
    const float* __restrict__ W_sp, const float* __restrict__ b_sp,
    const float* __restrict__ W_out, const float* __restrict__ b_out,
    float* __restrict__ out)
{
    __shared__ __align__(16) float pooled[64];
    __shared__ __align__(16) float social[64];
    __shared__ __align__(16) float hl[64];
    __shared__ __align__(16) float cl[64];
    __shared__ float gl[256];
    __shared__ __align__(16) float histl[32];
    __shared__ float xs[4];
    __shared__ float lp[2];
    const int tid = threadIdx.x;

    if (tid < 32) histl[tid] = history[tid];
    if (tid < 64) {
        float p = 0.0f;
        #pragma unroll
        for (int c = 0; c < CELLS; ++c) {
            const float cc = ws[CELLS * HDIM + c];
            p += ws[c * HDIM + tid] / fmaxf(cc, 1.0f);
        }
        pooled[tid] = p;
    }
    __syncthreads();
    if (tid < 64) {
        float s = b_sp[tid];
        for (int k = 0; k < 64; k += 4) {
            const float4 w4 = *(const float4*)&W_sp[tid * 64 + k];
            s += pooled[k] * w4.x + pooled[k + 1] * w4.y
               + pooled[k + 2] * w4.z + pooled[k + 3] * w4.w;
        }
        social[tid] = s;
        hl[tid] = 0.0f;
        cl[tid] = 0.0f;
    }
    if (tid == 0) { lp[0] = histl[28]; lp[1] = histl[29]; }
    __syncthreads();

    const float4 mv = *(const float4*)&ws[WS_M1K + tid * 4];
    float gconst = ws[WS_G0 + tid];
    for (int k = 0; k < 64; k += 4) {
        const float4 w4 = *(const float4*)&W_ih[tid * 128 + 64 + k];
        gconst += w4.x * social[k] + w4.y * social[k + 1]
                + w4.z * social[k + 2] + w4.w * social[k + 3];
    }
    float whh[64];
    #pragma unroll
    for (int k = 0; k < 64; k += 4) {
        const float4 w4 = *(const float4*)&W_hh[tid * 64 + k];
        whh[k] = w4.x; whh[k + 1] = w4.y; whh[k + 2] = w4.z; whh[k + 3] = w4.w;
    }
    float wout0 = 0.0f, wout1 = 0.0f, bo0 = 0.0f, bo1 = 0.0f;
    if (tid < 64) {
        wout0 = W_out[tid]; wout1 = W_out[64 + tid];
        bo0 = b_out[0]; bo1 = b_out[1];
    }
    __syncthreads();

    for (int t = 0; t < 8; ++t) {
        const float x0 = histl[t * 4 + 0], x1 = histl[t * 4 + 1];
        const float x2 = histl[t * 4 + 2], x3 = histl[t * 4 + 3];
        float g0 = gconst + mv.x * x0 + mv.y * x1;
        float g1 = mv.z * x2 + mv.w * x3;
        float g2 = 0.0f, g3 = 0.0f;
        #pragma unroll
        for (int k = 0; k < 64; k += 16) {
            const float4 a = *(const float4*)&hl[k];
            const float4 b = *(const float4*)&hl[k + 4];
            const float4 c = *(const float4*)&hl[k + 8];
            const float4 d = *(const float4*)&hl[k + 12];
            g0 += whh[k] * a.x + whh[k + 1] * a.y + whh[k + 2] * a.z + whh[k + 3] * a.w;
            g1 += whh[k + 4] * b.x + whh[k + 5] * b.y + whh[k + 6] * b.z + whh[k + 7] * b.w;
            g2 += whh[k + 8] * c.x + whh[k + 9] * c.y + whh[k + 10] * c.z + whh[k + 11] * c.w;
            g3 += whh[k + 12] * d.x + whh[k + 13] * d.y + whh[k + 14] * d.z + whh[k + 15] * d.w;
        }
        gl[tid] = (g0 + g1) + (g2 + g3);
        __syncthreads();
        if (tid < 64) {
            const float ig = 1.0f / (1.0f + expf(-gl[tid]));
            const float fg = 1.0f / (1.0f + expf(-gl[64 + tid]));
            const float gg = tanhf(gl[128 + tid]);
            const float og = 1.0f / (1.0f + expf(-gl[192 + tid]));
            const float cn = fg * cl[tid] + ig * gg;
            cl[tid] = cn;
            hl[tid] = og * tanhf(cn);
        }
        __syncthreads();
    }

    for (int t = 0; t < 12; ++t) {
        if (tid < 64) {
            float s0 = wout0 * hl[tid];
            float s1 = wout1 * hl[tid];
            #pragma unroll
            for (int off = 32; off > 0; off >>= 1) {
                s0 += __shfl_xor(s0, off);
                s1 += __shfl_xor(s1, off);
            }
            if (tid == 0) {
                const float d0 = s0 + bo0, d1 = s1 + bo1;
                out[t * 2 + 0] = d0;
                out[t * 2 + 1] = d1;
                const float n0 = lp[0] + d0, n1 = lp[1] + d1;
                xs[0] = n0; xs[1] = n1;
                xs[2] = d0 * 2.0f; xs[3] = d1 * 2.0f;
                lp[0] = n0; lp[1] = n1;
            }
        }
        __syncthreads();
        const float x0 = xs[0], x1 = xs[1], x2 = xs[2], x3 = xs[3];
        float g0 = gconst + mv.x * x0 + mv.y * x1;
        float g1 = mv.z * x2 + mv.w * x3;
        float g2 = 0.0f, g3 = 0.0f;
        #pragma unroll
        for (int k = 0; k < 64; k += 16) {
            const float4 a = *(const float4*)&hl[k];
            const float4 b = *(const float4*)&hl[k + 4];
            const float4 c = *(const float4*)&hl[k + 8];
            const float4 d = *(const float4*)&hl[k + 12];
            g0 += whh[k] * a.x + whh[k + 1] * a.y + whh[k + 2] * a.z + whh[k + 3] * a.w;
            g1 += whh[k + 4] * b.x + whh[k + 5] * b.y + whh[k + 6] * b.z + whh[k + 7] * b.w;
            g2 += whh[k + 8] * c.x + whh[k + 9] * c.y + whh[k + 10] * c.z + whh[k + 11] * c.w;
            g3 += whh[k + 12] * d.x + whh[k + 13] * d.y + whh[k + 14] * d.z + whh[k + 15] * d.w;
        }
        gl[tid] = (g0 + g1) + (g2 + g3);
        __syncthreads();
        if (tid < 64) {
            const float ig = 1.0f / (1.0f + expf(-gl[tid]));
            const float fg = 1.0f / (1.0f + expf(-gl[64 + tid]));
            const float gg = tanhf(gl[128 + tid]);
            const float og = 1.0f / (1.0f + expf(-gl[192 + tid]));
            const float cn = fg * cl[tid] + ig * gg;
            cl[tid] = cn;
            hl[tid] = og * tanhf(cn);
        }
        __syncthreads();
    }
}

extern "C" void kernel_launch(void* const* d_in, const int* in_sizes, int n_in,
                              void* d_out, int out_size, void* d_ws, size_t ws_size,
                              hipStream_t stream) {
    const float* history   = (const float*)d_in[0];
    const float* all_h     = (const float*)d_in[1];
    const float* positions = (const float*)d_in[2];
    const float* W_in  = (const float*)d_in[3];
    const float* b_in  = (const float*)d_in[4];
    const float* W_ih  = (const float*)d_in[5];
    const float* b_ih  = (const float*)d_in[6];
    const float* W_hh  = (const float*)d_in[7];
    const float* b_hh  = (const float*)d_in[8];
    const float* W_sp  = (const float*)d_in[9];
    const float* b_sp  = (const float*)d_in[10];
    const float* W_out = (const float*)d_in[11];
    const float* b_out = (const float*)d_in[12];
    const int*   idxp  = (const int*)d_in[13];
    const int N = in_sizes[2] / 2;

    float* ws      = (float*)d_ws;
    float* partial = ws + WS_PART;

    long long avail = (long long)(ws_size / sizeof(float)) - WS_PART;
    int nbp = 2048;             // 8 pool blocks/CU, whole grid co-resident
    if ((long long)nbp * PV > avail) nbp = (int)(avail / PV);
    if (nbp < 1) nbp = 1;

    k_pool<<<nbp + 1, 256, 0, stream>>>(all_h, (const float2*)positions, idxp,
                                        partial, ws, W_in, b_in, W_ih, b_ih,
                                        W_hh, b_hh, W_sp, W_out, N, nbp * WPB);
    k_reduce<<<65, 256, 0, stream>>>(partial, ws, nbp);
    k_lstm<<<1, 256, 0, stream>>>(ws, history, W_ih, W_hh, W_sp, b_sp,
                                  W_out, b_out, (float*)d_out);
}